// Round 1
// baseline (2934.872 us; speedup 1.0000x reference)
//
#include <hip/hip_runtime.h>
#include <hip/hip_fp16.h>

// RNN: B=256 T=2048 I=64 H=256. One workgroup (256 thr) per batch sample,
// one output element per thread. W rows live in VGPRs as packed f16 pairs;
// h lives in LDS (f16, double-buffered); x staged in 16-step blocks.
// Inner product via v_dot2_f32_f16 (fp32 accumulate) when available.

static constexpr int nB = 256;
static constexpr int nT = 2048;
static constexpr int nI = 64;
static constexpr int nH = 256;
static constexpr int XBLK = 16;   // timesteps of x staged per block

typedef _Float16 h2_t __attribute__((ext_vector_type(2)));
union H2U { unsigned int u; h2_t h; };

__device__ __forceinline__ unsigned int pack2(float a, float b) {
  H2U r; r.h = h2_t{(_Float16)a, (_Float16)b}; return r.u;
}

__device__ __forceinline__ float dot2f(unsigned int a, unsigned int b, float c) {
#if __has_builtin(__builtin_amdgcn_fdot2)
  H2U ua; ua.u = a; H2U ub; ub.u = b;
  return __builtin_amdgcn_fdot2(ua.h, ub.h, c, false);
#else
  // fallback: v_fma_mix_f32 path (fp32 rate, still correct)
  H2U ua; ua.u = a; H2U ub; ub.u = b;
  float r = c;
  r = fmaf((float)ua.h.x, (float)ub.h.x, r);
  r = fmaf((float)ua.h.y, (float)ub.h.y, r);
  return r;
#endif
}

__device__ __forceinline__ float fast_tanh(float x) {
  float a = fabsf(x);
  float e = __expf(-2.0f * a);            // in (0,1], never overflows
  float r = (1.0f - e) / (1.0f + e);      // tanh(|x|)
  return copysignf(r, x);
}

__global__ __launch_bounds__(256, 1)
void rnn_fused(const float* __restrict__ x, const int* __restrict__ lengths,
               const float* __restrict__ Wih, const float* __restrict__ Whh,
               const float* __restrict__ bih, const float* __restrict__ bhh,
               const float* __restrict__ Wfc, const float* __restrict__ bfc,
               float* __restrict__ out)
{
  // LDS: x blocks (2 x 16 steps x 64 f16 = 4 KB), h (2 x 256 f16 = 1 KB)
  __shared__ __align__(16) unsigned int xbuf[2][XBLK * nI / 2];
  __shared__ __align__(16) unsigned int hbuf[2][nH / 2];
  __shared__ float red[4];

  const int b   = blockIdx.x;
  const int tid = threadIdx.x;            // output index j
  const int len = lengths[b];             // in [1, nT]

  const float* xb = x + (size_t)b * nT * nI;

  // ---- preamble: pack this thread's weight rows into registers (f16 pairs)
  unsigned int wih[nI / 2];               // 32 VGPRs
  unsigned int whh[nH / 2];               // 128 VGPRs
  {
    const float* wr = Wih + tid * nI;
#pragma unroll
    for (int c = 0; c < nI / 2; ++c) wih[c] = pack2(wr[2 * c], wr[2 * c + 1]);
    const float* hr = Whh + tid * nH;
#pragma unroll
    for (int c = 0; c < nH / 2; ++c) whh[c] = pack2(hr[2 * c], hr[2 * c + 1]);
  }
  const float bias = bih[tid] + bhh[tid];

  // ---- h0 = 0; stage x block 0 (256 thr x float4 = 16 steps x 64 floats)
  if (tid < nH / 2) hbuf[0][tid] = 0u;
  {
    float4 v = *(const float4*)(xb + tid * 4);
    xbuf[0][tid * 2]     = pack2(v.x, v.y);
    xbuf[0][tid * 2 + 1] = pack2(v.z, v.w);
  }
  __syncthreads();

  // ---- main recurrence
  int t = 0;
  for (int blk = 0; t < len; ++blk) {
    // prefetch next x block into registers while computing this one
    float4 pre;
    const bool havepre = ((blk + 1) * XBLK < len);
    if (havepre)
      pre = *(const float4*)(xb + (size_t)(blk + 1) * XBLK * nI + tid * 4);

    const int nsteps = min(XBLK, len - blk * XBLK);
    const unsigned int* xrow0 = xbuf[blk & 1];

    for (int s = 0; s < nsteps; ++s, ++t) {
      const uint4* xp4 = (const uint4*)(xrow0 + s * (nI / 2));
      const uint4* hp4 = (const uint4*)(hbuf[t & 1]);

      // 8 independent accumulator chains (dot2 latency hiding at 1 wave/SIMD)
      float acc[8];
      acc[0] = bias;
#pragma unroll
      for (int i = 1; i < 8; ++i) acc[i] = 0.0f;

#pragma unroll
      for (int p = 0; p < nI / 8; ++p) {          // input projection: 8 uint4
        uint4 v = xp4[p];
        const int q = (p & 1) ? 4 : 0;
        acc[q + 0] = dot2f(wih[4 * p + 0], v.x, acc[q + 0]);
        acc[q + 1] = dot2f(wih[4 * p + 1], v.y, acc[q + 1]);
        acc[q + 2] = dot2f(wih[4 * p + 2], v.z, acc[q + 2]);
        acc[q + 3] = dot2f(wih[4 * p + 3], v.w, acc[q + 3]);
      }
#pragma unroll
      for (int p = 0; p < nH / 8; ++p) {          // recurrence: 32 uint4
        uint4 v = hp4[p];
        const int q = (p & 1) ? 4 : 0;
        acc[q + 0] = dot2f(whh[4 * p + 0], v.x, acc[q + 0]);
        acc[q + 1] = dot2f(whh[4 * p + 1], v.y, acc[q + 1]);
        acc[q + 2] = dot2f(whh[4 * p + 2], v.z, acc[q + 2]);
        acc[q + 3] = dot2f(whh[4 * p + 3], v.w, acc[q + 3]);
      }
      float s01 = (acc[0] + acc[4]) + (acc[1] + acc[5]);
      float s23 = (acc[2] + acc[6]) + (acc[3] + acc[7]);
      float hnew = fast_tanh(s01 + s23);

      ((__half*)hbuf[(t + 1) & 1])[tid] = __float2half(hnew);
      __syncthreads();   // writes to buf (t+1)&1 visible; reads of buf t&1 done
    }

    if (havepre) {
      unsigned int* xd = xbuf[(blk + 1) & 1];
      xd[tid * 2]     = pack2(pre.x, pre.y);
      xd[tid * 2 + 1] = pack2(pre.z, pre.w);
    }
    __syncthreads();     // x block visible before next outer iteration reads it
  }

  // ---- epilogue: out[b] = h_len . W_fc + b_fc   (h_final is in hbuf[len&1])
  float v = (float)((const __half*)hbuf[len & 1])[tid] * Wfc[tid];
#pragma unroll
  for (int off = 32; off > 0; off >>= 1) v += __shfl_down(v, off);
  if ((tid & 63) == 0) red[tid >> 6] = v;
  __syncthreads();
  if (tid == 0) out[b] = (red[0] + red[1]) + (red[2] + red[3]) + bfc[0];
}

extern "C" void kernel_launch(void* const* d_in, const int* in_sizes, int n_in,
                              void* d_out, int out_size, void* d_ws, size_t ws_size,
                              hipStream_t stream) {
  const float* x   = (const float*)d_in[0];
  const int* lens  = (const int*)d_in[1];
  const float* Wih = (const float*)d_in[2];
  const float* Whh = (const float*)d_in[3];
  const float* bih = (const float*)d_in[4];
  const float* bhh = (const float*)d_in[5];
  const float* Wfc = (const float*)d_in[6];
  const float* bfc = (const float*)d_in[7];
  float* out = (float*)d_out;

  rnn_fused<<<nB, 256, 0, stream>>>(x, lens, Wih, Whh, bih, bhh, Wfc, bfc, out);
}

// Round 2
// 1217.968 us; speedup vs baseline: 2.4096x; 2.4096x over previous
//
#include <hip/hip_runtime.h>

// RNN B=256 T=2048 I=64 H=256 — one workgroup per sample (256 CUs), MFMA matvec.
// h_t = tanh(W_ih x_t + W_hh h_{t-1} + b). Weights live in VGPRs as f16 A-fragments
// (loaded once); h and x live in LDS as f16 in B-operand layout (contiguous).
// B replicated across all 16 N-columns => every C column is a valid matvec copy;
// column-split ownership gives 1 tanh + 1 ds_write_b16 per lane per step.
// 512 thr = 8 waves = 2 waves/SIMD for latency hiding; one barrier per step.

static constexpr int nB = 256;
static constexpr int nT = 2048;
static constexpr int nI = 64;
static constexpr int nH = 256;
static constexpr int XBLK = 32;     // timesteps of x staged per block
static constexpr int THREADS = 512; // 8 waves; wave w owns output rows [32w,32w+32)

typedef _Float16 f16x8 __attribute__((ext_vector_type(8)));
typedef float f32x4 __attribute__((ext_vector_type(4)));

__device__ __forceinline__ float fast_tanh(float x) {
  float a = fabsf(x);
  float e = __expf(-2.0f * a);           // in (0,1], never overflows
  float r = (1.0f - e) / (1.0f + e);
  return copysignf(r, x);
}

__global__ __launch_bounds__(THREADS, 2)
void rnn_mfma(const float* __restrict__ x, const int* __restrict__ lengths,
              const float* __restrict__ Wih, const float* __restrict__ Whh,
              const float* __restrict__ bih, const float* __restrict__ bhh,
              const float* __restrict__ Wfc, const float* __restrict__ bfc,
              float* __restrict__ out)
{
  __shared__ __align__(16) _Float16 hbuf[2][nH];          // 1 KB
  __shared__ __align__(16) _Float16 xbuf[2][XBLK * nI];   // 8 KB
  __shared__ float red[THREADS / 64];

  const int b   = blockIdx.x;
  const int tid = threadIdx.x;
  const int w   = tid >> 6;       // wave 0..7
  const int l   = tid & 63;
  const int q   = l >> 4;         // quad 0..3
  const int n   = l & 15;         // MFMA column lane
  const int len = lengths[b];     // in [1, nT]
  const float* xb = x + (size_t)b * nT * nI;

  // ---- preamble: pack this wave's W rows into A-fragments (f16)
  // A layout (16x16x32): lane holds A[m = lane&15][k = 8*(lane>>4) + j], j=0..7
  f16x8 Ah[2][8];   // [m-tile][k-tile] over W_hh, rows 32w+16mt+n, k 32kt+8q+j
  f16x8 Ax[2][2];   // over W_ih (I=64 -> 2 k-tiles)
#pragma unroll
  for (int mt = 0; mt < 2; ++mt) {
    const int row = 32 * w + 16 * mt + n;
#pragma unroll
    for (int kt = 0; kt < 8; ++kt) {
      const float* src = Whh + row * nH + 32 * kt + 8 * q;
      f16x8 a;
#pragma unroll
      for (int j = 0; j < 8; ++j) a[j] = (_Float16)src[j];
      Ah[mt][kt] = a;
    }
#pragma unroll
    for (int kt = 0; kt < 2; ++kt) {
      const float* src = Wih + row * nI + 32 * kt + 8 * q;
      f16x8 a;
#pragma unroll
      for (int j = 0; j < 8; ++j) a[j] = (_Float16)src[j];
      Ax[mt][kt] = a;
    }
  }
  // bias in C layout: reg r <-> row 32w + 16mt + 4q + r (same for every column)
  f32x4 bias0, bias1;
#pragma unroll
  for (int r = 0; r < 4; ++r) {
    const int r0 = 32 * w + 4 * q + r;
    bias0[r] = bih[r0] + bhh[r0];
    bias1[r] = bih[r0 + 16] + bhh[r0 + 16];
  }
  // column-split ownership: column lane n<8 owns (m-tile n>>2, reg n&3)
  const int mt_sel  = (n >> 2) & 1;
  const int reg_sel = n & 3;
  const int row_own = 32 * w + 16 * mt_sel + 4 * q + reg_sel;

  // ---- h0 = 0; stage x block 0 (512 thr x float4 = 32 steps x 64 floats)
  if (tid < nH) hbuf[0][tid] = (_Float16)0.f;
  {
    float4 v = *(const float4*)(xb + tid * 4);
    _Float16* d = xbuf[0] + tid * 4;
    d[0] = (_Float16)v.x; d[1] = (_Float16)v.y;
    d[2] = (_Float16)v.z; d[3] = (_Float16)v.w;
  }
  __syncthreads();

  // ---- main recurrence: one __syncthreads per step (h double-buffered)
  int t = 0;
  for (int blk = 0; t < len; ++blk) {
    float4 pre;
    const bool havepre = ((blk + 1) * XBLK < len);
    if (havepre)
      pre = *(const float4*)(xb + (size_t)(blk + 1) * XBLK * nI + tid * 4);

    const int nsteps = min(XBLK, len - blk * XBLK);
    const _Float16* xB = xbuf[blk & 1];

    for (int s = 0; s < nsteps; ++s, ++t) {
      const _Float16* hsrc = hbuf[t & 1];
      const _Float16* xsrc = xB + s * nI;

      f32x4 acc0 = bias0, acc1 = bias1;
      // W_hh . h : 8 K-tiles; B-frag = ds_read_b128, broadcast across columns
#pragma unroll
      for (int kt = 0; kt < 8; ++kt) {
        f16x8 Bh = *(const f16x8*)(hsrc + 32 * kt + 8 * q);
        acc0 = __builtin_amdgcn_mfma_f32_16x16x32_f16(Ah[0][kt], Bh, acc0, 0, 0, 0);
        acc1 = __builtin_amdgcn_mfma_f32_16x16x32_f16(Ah[1][kt], Bh, acc1, 0, 0, 0);
      }
      // W_ih . x_t : 2 K-tiles (fused input projection)
#pragma unroll
      for (int kt = 0; kt < 2; ++kt) {
        f16x8 Bx = *(const f16x8*)(xsrc + 32 * kt + 8 * q);
        acc0 = __builtin_amdgcn_mfma_f32_16x16x32_f16(Ax[0][kt], Bx, acc0, 0, 0, 0);
        acc1 = __builtin_amdgcn_mfma_f32_16x16x32_f16(Ax[1][kt], Bx, acc1, 0, 0, 0);
      }

      // every column holds a valid copy; this lane finishes exactly one output
      f32x4 a = mt_sel ? acc1 : acc0;
      float lo = (reg_sel & 1) ? a[1] : a[0];
      float hi = (reg_sel & 1) ? a[3] : a[2];
      float v  = (reg_sel & 2) ? hi : lo;
      float hn = fast_tanh(v);

      // fold next-x writeback in before the last step's barrier of this block
      if (s == nsteps - 1 && havepre) {
        _Float16* d = xbuf[(blk + 1) & 1] + tid * 4;
        d[0] = (_Float16)pre.x; d[1] = (_Float16)pre.y;
        d[2] = (_Float16)pre.z; d[3] = (_Float16)pre.w;
      }
      if (n < 8) hbuf[(t + 1) & 1][row_own] = (_Float16)hn;
      __syncthreads();
    }
  }

  // ---- epilogue: out[b] = h_final . W_fc + b_fc
  float v = 0.f;
  if (tid < nH) v = (float)hbuf[len & 1][tid] * Wfc[tid];
#pragma unroll
  for (int off = 32; off; off >>= 1) v += __shfl_down(v, off);
  if (l == 0) red[w] = v;
  __syncthreads();
  if (tid == 0) {
    float acc = bfc[0];
#pragma unroll
    for (int i = 0; i < THREADS / 64; ++i) acc += red[i];
    out[b] = acc;
  }
}

extern "C" void kernel_launch(void* const* d_in, const int* in_sizes, int n_in,
                              void* d_out, int out_size, void* d_ws, size_t ws_size,
                              hipStream_t stream) {
  const float* x   = (const float*)d_in[0];
  const int* lens  = (const int*)d_in[1];
  const float* Wih = (const float*)d_in[2];
  const float* Whh = (const float*)d_in[3];
  const float* bih = (const float*)d_in[4];
  const float* bhh = (const float*)d_in[5];
  const float* Wfc = (const float*)d_in[6];
  const float* bfc = (const float*)d_in[7];
  float* out = (float*)d_out;

  rnn_mfma<<<nB, THREADS, 0, stream>>>(x, lens, Wih, Whh, bih, bhh, Wfc, bfc, out);
}